// Round 10
// baseline (296.366 us; speedup 1.0000x reference)
//
#include <hip/hip_runtime.h>

#define T_STEPS 512
#define HSTR 80        // _Float16 per h batch-row (160 B): A-read max 2-way = free
#define XSTRIDE 520    // _Float16 per x-row
#define OSTRIDE 513    // floats per out-row
#define NB 4           // batches per block -> 512 blocks = 2 independent blocks/CU

typedef _Float16 half8v __attribute__((ext_vector_type(8)));
typedef _Float16 half4v __attribute__((ext_vector_type(4)));
typedef float f32x4 __attribute__((ext_vector_type(4)));

#define K1 1.442695041f    // log2(e)
#define K2 2.885390082f    // 2*log2(e)

__device__ __forceinline__ float ex2(float x) {
#if __has_builtin(__builtin_amdgcn_exp2f)
    return __builtin_amdgcn_exp2f(x);
#else
    return exp2f(x);
#endif
}
__device__ __forceinline__ float rcp_fast(float x) {
#if __has_builtin(__builtin_amdgcn_rcpf)
    return __builtin_amdgcn_rcpf(x);
#else
    return 1.0f / x;
#endif
}

// partial fc-dot over this lane's A-frag slice (f16), reduced over the 4 k-quads
__device__ __forceinline__ float out_dot(half8v a0, half8v a1,
                                         const float* wfc0, const float* wfc1) {
    float s = 0.f;
#pragma unroll
    for (int j = 0; j < 8; ++j) s = fmaf((float)a0[j], wfc0[j], s);
#pragma unroll
    for (int j = 0; j < 8; ++j) s = fmaf((float)a1[j], wfc1[j], s);
    s += __shfl_xor(s, 16);
    s += __shfl_xor(s, 32);
    return s;   // full 64-dot for batch (lane&3), on all lanes
}

// 256 thr = 4 waves, NB=4 batches, 512 blocks = 2 blocks/CU (independent
// barriers -> chains interleave). Wave w owns units 16w..16w+15. A-frag read
// replicates row m -> h[m&3]; D row 4q+r = batch r, so lane (q,c) selects
// element q (3 cndmask) and owns exactly one (batch q, unit 16w+c) pair.
// Weights prescaled by -log2e / 2log2e; MFMA C-init from a persistent zero
// quad; x*wih+bias folded in AFTER the batch select (scalar, 2 ops/gate).
__global__ __launch_bounds__(256, 1) void lstm_kernel(
    const float* __restrict__ x, const float* __restrict__ w_ih,
    const float* __restrict__ w_hh, const float* __restrict__ b_ih,
    const float* __restrict__ b_hh, const float* __restrict__ w_fc,
    const float* __restrict__ b_fc, float* __restrict__ out)
{
    __shared__ __align__(16) _Float16 hbuf[2][NB * HSTR];  // 1.25 KB
    __shared__ __align__(16) _Float16 xls[NB * XSTRIDE];   // 4.2 KB
    __shared__ __align__(16) float ols[NB * OSTRIDE];      // 8.2 KB

    const int tid  = threadIdx.x;
    const int w    = tid >> 6;        // wave 0..3
    const int lane = tid & 63;
    const int q    = lane >> 4;       // quad: k-group, D row-group, OWN BATCH
    const int c    = lane & 15;       // unit-in-tile / A-row
    const int b0   = blockIdx.x * NB;

    // ---- stage x: global -> LDS (f16), coalesced float4 reads ----
    for (int i = tid; i < NB * 128; i += 256) {      // 4 rows x 128 float4
        int b  = i >> 7;
        int t4 = i & 127;
        float4 v = *(const float4*)(x + (size_t)(b0 + b) * T_STEPS + t4 * 4);
        half4v hv;
        hv[0] = (_Float16)v.x; hv[1] = (_Float16)v.y;
        hv[2] = (_Float16)v.z; hv[3] = (_Float16)v.w;
        *(half4v*)(&xls[b * XSTRIDE + t4 * 4]) = hv;
    }
    // zero both h buffers (h_{-1} = 0)
    for (int i = tid; i < 2 * NB * HSTR / 2; i += 256) ((int*)hbuf)[i] = 0;

    // ---- B fragments (prescaled weights): tile n = gate class ----
    // lane (q,c) holds B[k=32kk+8q+jj][col c] = sK[n]*w_hh[g][k], g = 64n+16w+c
    const float sK[4] = { -K1, -K1, K2, -K1 };   // i,f sig; g tanh; o sig
    half8v bfrag[4][2];
    float biasS[4], wihS[4];
#pragma unroll
    for (int n = 0; n < 4; ++n) {
        int g = 64 * n + 16 * w + c;
        biasS[n] = (b_ih[g] + b_hh[g]) * sK[n];
        wihS[n]  = w_ih[g] * sK[n];
#pragma unroll
        for (int kk = 0; kk < 2; ++kk) {
            const float* wp = w_hh + g * 64 + 32 * kk + 8 * q;
            float4 lo  = *(const float4*)(wp);
            float4 hi4 = *(const float4*)(wp + 4);
            half8v f;
            f[0] = (_Float16)(lo.x  * sK[n]); f[1] = (_Float16)(lo.y  * sK[n]);
            f[2] = (_Float16)(lo.z  * sK[n]); f[3] = (_Float16)(lo.w  * sK[n]);
            f[4] = (_Float16)(hi4.x * sK[n]); f[5] = (_Float16)(hi4.y * sK[n]);
            f[6] = (_Float16)(hi4.z * sK[n]); f[7] = (_Float16)(hi4.w * sK[n]);
            bfrag[n][kk] = f;
        }
    }

    // fc weights aligned to this lane's A-frag k-slice
    float wfc0[8], wfc1[8];
#pragma unroll
    for (int j = 0; j < 8; ++j) { wfc0[j] = w_fc[8 * q + j]; wfc1[j] = w_fc[32 + 8 * q + j]; }
    const float bfc = b_fc[0];

    // batch-select masks (hoisted): pick element q out of acc[n][0..3]
    const bool qb0 = q & 1, qb1 = q & 2;

    float cs = 0.f;             // cell state for (batch q, unit 16w+c)
    const f32x4 zeroq = {0.f, 0.f, 0.f, 0.f};

    __syncthreads();

    half8v sa0 = {}, sa1 = {};  // saved A-frags for rotated fc-dot

    for (int tq = 0; tq < 128; ++tq) {
        // own batch's x, 4 steps (16-lane broadcast read)
        half4v xh = *(const half4v*)(&xls[q * XSTRIDE + tq * 4]);

#pragma unroll
        for (int dt = 0; dt < 4; ++dt) {
            const int t  = tq * 4 + dt;
            const int rb = t & 1;
            const _Float16* hrd = hbuf[rb];

            // A-frags: A[m][k] = h[m&3][k]; lane row m=c -> LDS row c&3
            const _Float16* hp = hrd + (c & 3) * HSTR + 8 * q;
            half8v a0 = *(const half8v*)(hp);        // k = 8q+j
            half8v a1 = *(const half8v*)(hp + 32);   // k = 32+8q+j

            if (dt == w) { sa0 = a0; sa1 = a1; }     // rotate fc-dot ownership

            // scalar x*wih+bias for this lane's batch (independent of MFMA)
            const float xv = (float)xh[dt];
            float xb[4];
#pragma unroll
            for (int n = 0; n < 4; ++n) xb[n] = fmaf(xv, wihS[n], biasS[n]);

            // gates: 4 class tiles, K=64 via chained MFMA pair, C = 0
            f32x4 acc[4];
#pragma unroll
            for (int n = 0; n < 4; ++n) {
                acc[n] = __builtin_amdgcn_mfma_f32_16x16x32_f16(a1, bfrag[n][1], zeroq, 0, 0, 0);
                acc[n] = __builtin_amdgcn_mfma_f32_16x16x32_f16(a0, bfrag[n][0], acc[n], 0, 0, 0);
            }

            // batch select: element q of each acc (D row 4q+r = batch r)
            float v[4];
#pragma unroll
            for (int n = 0; n < 4; ++n) {
                float lo = qb0 ? acc[n][1] : acc[n][0];
                float hi = qb0 ? acc[n][3] : acc[n][2];
                v[n] = (qb1 ? hi : lo) + xb[n];
            }

            // fused activations (args pre-scaled); one (batch,unit) pair
            {
                float A  = ex2(v[0]);                  // e^{-i}
                float B  = ex2(v[2]);                  // e^{2g}
                float ig = (B - 1.0f) * rcp_fast((1.0f + A) * (1.0f + B));
                float rf = rcp_fast(1.0f + ex2(v[1])); // sig(f)
                cs = fmaf(cs, rf, ig);
                float cc = fminf(fmaxf(cs, -15.f), 15.f);
                float Ao = ex2(v[3]);                  // e^{-o}
                float C  = ex2(cc * K2);               // e^{2c}
                float h  = (C - 1.0f) * rcp_fast((1.0f + Ao) * (1.0f + C));
                hbuf[rb ^ 1][q * HSTR + 16 * w + c] = (_Float16)h;
            }
            __syncthreads();
        }

        // rotated fc-dot: saved frag is A of step st = tq*4+w = h_{st-1};
        // after reduction lane b (b<4) holds batch b's dot (b = lane&3)
        {
            int st = tq * 4 + w;
            if (st > 0) {
                float s = out_dot(sa0, sa1, wfc0, wfc1);
                if (lane < NB) ols[lane * OSTRIDE + (st - 1)] = s + bfc;
            }
        }
    }

    // final output column: h_511 lives in hbuf[0]
    if (w == 3) {
        const _Float16* hp = hbuf[0] + (c & 3) * HSTR + 8 * q;
        half8v a0 = *(const half8v*)(hp);
        half8v a1 = *(const half8v*)(hp + 32);
        float s = out_dot(a0, a1, wfc0, wfc1);
        if (lane < NB) ols[lane * OSTRIDE + (T_STEPS - 1)] = s + bfc;
    }
    __syncthreads();

    // bulk store: LDS out -> global, coalesced
    for (int i = tid; i < NB * T_STEPS; i += 256) {
        int b = i >> 9;
        int t = i & (T_STEPS - 1);
        out[(size_t)(b0 + b) * T_STEPS + t] = ols[b * OSTRIDE + t];
    }
}

extern "C" void kernel_launch(void* const* d_in, const int* in_sizes, int n_in,
                              void* d_out, int out_size, void* d_ws, size_t ws_size,
                              hipStream_t stream) {
    const float* x    = (const float*)d_in[0];
    const float* w_ih = (const float*)d_in[1];
    const float* w_hh = (const float*)d_in[2];
    const float* b_ih = (const float*)d_in[3];
    const float* b_hh = (const float*)d_in[4];
    const float* w_fc = (const float*)d_in[5];
    const float* b_fc = (const float*)d_in[6];
    float* out = (float*)d_out;
    hipLaunchKernelGGL(lstm_kernel, dim3(2048 / NB), dim3(256), 0, stream,
                       x, w_ih, w_hh, b_ih, b_hh, w_fc, b_fc, out);
}

// Round 11
// 263.712 us; speedup vs baseline: 1.1238x; 1.1238x over previous
//
#include <hip/hip_runtime.h>

#define T_STEPS 512
#define HSTR 80        // _Float16 per h batch-row (160 B): A-reads max 2-way = free
#define XSTRIDE 520    // _Float16 per x-row
#define OSTRIDE 513    // floats per out-row
#define NB 8           // batches per block, 256 blocks = 1 block/CU

typedef _Float16 half8v __attribute__((ext_vector_type(8)));
typedef _Float16 half4v __attribute__((ext_vector_type(4)));
typedef float f32x4 __attribute__((ext_vector_type(4)));

#define K1 1.442695041f    // log2(e)
#define K2 2.885390082f    // 2*log2(e)

__device__ __forceinline__ float ex2(float x) {
#if __has_builtin(__builtin_amdgcn_exp2f)
    return __builtin_amdgcn_exp2f(x);
#else
    return exp2f(x);
#endif
}
__device__ __forceinline__ float rcp_fast(float x) {
#if __has_builtin(__builtin_amdgcn_rcpf)
    return __builtin_amdgcn_rcpf(x);
#else
    return 1.0f / x;
#endif
}

// partial fc-dot over this lane's A-frag slice (f16), reduced over the 4 k-quads
__device__ __forceinline__ float out_dot(half8v a0, half8v a1,
                                         const float* wfc0, const float* wfc1) {
    float s = 0.f;
#pragma unroll
    for (int j = 0; j < 8; ++j) s = fmaf((float)a0[j], wfc0[j], s);
#pragma unroll
    for (int j = 0; j < 8; ++j) s = fmaf((float)a1[j], wfc1[j], s);
    s += __shfl_xor(s, 16);
    s += __shfl_xor(s, 32);
    return s;   // full 64-dot for batch (lane&7), on all lanes
}

// R9 champion structure + R10's proven deltas.
// 256 thr = 4 waves, 8 batches/block, 256 blocks. Wave w owns units 16w..16w+15.
// A-frag read replicates row m -> h[m&7]; D rows 8-15 duplicate batches 0-7.
// Lane (q,c): hq=q>>1 picks acc elems {2hq,2hq+1}; owns batches bat0,bat0+1,
// unit 16w+c. Weights prescaled by -log2e (i,f,o) / 2log2e (g); MFMA C-init
// is zero, x*wih+bias folded in after the batch select (8 fma, owned rows only).
__global__ __launch_bounds__(256, 1) void lstm_kernel(
    const float* __restrict__ x, const float* __restrict__ w_ih,
    const float* __restrict__ w_hh, const float* __restrict__ b_ih,
    const float* __restrict__ b_hh, const float* __restrict__ w_fc,
    const float* __restrict__ b_fc, float* __restrict__ out)
{
    __shared__ __align__(16) _Float16 hbuf[2][8 * HSTR];   // 2.5 KB
    __shared__ __align__(16) _Float16 xls[NB * XSTRIDE];   // 8.3 KB
    __shared__ __align__(16) float ols[NB * OSTRIDE];      // 16.4 KB

    const int tid  = threadIdx.x;
    const int w    = tid >> 6;        // wave 0..3
    const int lane = tid & 63;
    const int q    = lane >> 4;       // quad (A k-group / D row-group)
    const int c    = lane & 15;       // unit-in-tile / A-row
    const int hq   = q >> 1;          // 0: use acc elems {0,1}; 1: elems {2,3}
    const int bat0 = 4 * (q & 1) + 2 * hq;  // first of this lane's 2 batches
    const int b0   = blockIdx.x * NB;

    // ---- stage x: global -> LDS (f16), coalesced float4 reads ----
    for (int i = tid; i < NB * 128; i += 256) {      // 8 rows x 128 float4
        int b  = i >> 7;
        int t4 = i & 127;
        float4 v = *(const float4*)(x + (size_t)(b0 + b) * T_STEPS + t4 * 4);
        half4v hv;
        hv[0] = (_Float16)v.x; hv[1] = (_Float16)v.y;
        hv[2] = (_Float16)v.z; hv[3] = (_Float16)v.w;
        *(half4v*)(&xls[b * XSTRIDE + t4 * 4]) = hv;
    }
    // zero both h buffers (h_{-1} = 0): 2*8*80 f16 = 640 dwords
    for (int i = tid; i < 2 * 8 * HSTR / 2; i += 256) ((int*)hbuf)[i] = 0;

    // ---- B fragments (prescaled weights): tile n = gate class ----
    // lane (q,c) holds B[k=32kk+8q+jj][col c] = sK[n]*w_hh[g][k], g = 64n+16w+c
    const float sK[4] = { -K1, -K1, K2, -K1 };   // i,f sig; g tanh; o sig
    half8v bfrag[4][2];
    float biasS[4], wihS[4];
#pragma unroll
    for (int n = 0; n < 4; ++n) {
        int g = 64 * n + 16 * w + c;
        biasS[n] = (b_ih[g] + b_hh[g]) * sK[n];
        wihS[n]  = w_ih[g] * sK[n];
#pragma unroll
        for (int kk = 0; kk < 2; ++kk) {
            const float* wp = w_hh + g * 64 + 32 * kk + 8 * q;
            float4 lo  = *(const float4*)(wp);
            float4 hi4 = *(const float4*)(wp + 4);
            half8v f;
            f[0] = (_Float16)(lo.x  * sK[n]); f[1] = (_Float16)(lo.y  * sK[n]);
            f[2] = (_Float16)(lo.z  * sK[n]); f[3] = (_Float16)(lo.w  * sK[n]);
            f[4] = (_Float16)(hi4.x * sK[n]); f[5] = (_Float16)(hi4.y * sK[n]);
            f[6] = (_Float16)(hi4.z * sK[n]); f[7] = (_Float16)(hi4.w * sK[n]);
            bfrag[n][kk] = f;
        }
    }

    // fc weights aligned to this lane's A-frag k-slice
    float wfc0[8], wfc1[8];
#pragma unroll
    for (int j = 0; j < 8; ++j) { wfc0[j] = w_fc[8 * q + j]; wfc1[j] = w_fc[32 + 8 * q + j]; }
    const float bfc = b_fc[0];

    float cs[2] = {0.f, 0.f};   // cell state for (batch bat0+rr, unit 16w+c)
    const f32x4 zeroq = {0.f, 0.f, 0.f, 0.f};

    __syncthreads();

    half8v sa0 = {}, sa1 = {};  // saved A-frags for rotated fc-dot

    for (int tq = 0; tq < 128; ++tq) {
        // x for this lane's OWN 2 batches, 4 steps (broadcast reads)
        half4v xh0 = *(const half4v*)(&xls[bat0 * XSTRIDE + tq * 4]);
        half4v xh1 = *(const half4v*)(&xls[(bat0 + 1) * XSTRIDE + tq * 4]);

#pragma unroll
        for (int dt = 0; dt < 4; ++dt) {
            const int t  = tq * 4 + dt;
            const int rb = t & 1;
            const _Float16* hrd = hbuf[rb];

            // A-frags: A[m][k] = h[m&7][k]; lane row m=c -> LDS row c&7
            const _Float16* hp = hrd + (c & 7) * HSTR + 8 * q;
            half8v a0 = *(const half8v*)(hp);        // k = 8q+j
            half8v a1 = *(const half8v*)(hp + 32);   // k = 32+8q+j

            if (dt == w) { sa0 = a0; sa1 = a1; }     // rotate fc-dot ownership

            // scalar x*wih+bias for the 2 owned batches (independent of MFMA)
            const float xv0 = (float)xh0[dt], xv1 = (float)xh1[dt];
            float xb0[4], xb1[4];
#pragma unroll
            for (int n = 0; n < 4; ++n) {
                xb0[n] = fmaf(xv0, wihS[n], biasS[n]);
                xb1[n] = fmaf(xv1, wihS[n], biasS[n]);
            }

            // gates: 4 class tiles, K=64 via chained MFMA pair, C = 0
            f32x4 acc[4];
#pragma unroll
            for (int n = 0; n < 4; ++n) {
                acc[n] = __builtin_amdgcn_mfma_f32_16x16x32_f16(a1, bfrag[n][1], zeroq, 0, 0, 0);
                acc[n] = __builtin_amdgcn_mfma_f32_16x16x32_f16(a0, bfrag[n][0], acc[n], 0, 0, 0);
            }

            // batch select (1 cndmask each) + x/bias fold
            float v[4][2];
#pragma unroll
            for (int n = 0; n < 4; ++n) {
                v[n][0] = (hq ? acc[n][2] : acc[n][0]) + xb0[n];
                v[n][1] = (hq ? acc[n][3] : acc[n][1]) + xb1[n];
            }

            // fused activations (args pre-scaled); lane owns (bat0+rr, 16w+c)
            _Float16* hwr = hbuf[rb ^ 1];
#pragma unroll
            for (int rr = 0; rr < 2; ++rr) {
                float A  = ex2(v[0][rr]);                  // e^{-i}
                float B  = ex2(v[2][rr]);                  // e^{2g}
                float ig = (B - 1.0f) * rcp_fast((1.0f + A) * (1.0f + B));
                float rf = rcp_fast(1.0f + ex2(v[1][rr])); // sig(f)
                cs[rr] = fmaf(cs[rr], rf, ig);
                float cc = fminf(fmaxf(cs[rr], -15.f), 15.f);
                float Ao = ex2(v[3][rr]);                  // e^{-o}
                float C  = ex2(cc * K2);                   // e^{2c}
                float h  = (C - 1.0f) * rcp_fast((1.0f + Ao) * (1.0f + C));
                hwr[(bat0 + rr) * HSTR + 16 * w + c] = (_Float16)h;
            }
            __syncthreads();
        }

        // rotated fc-dot: saved frag is A of step st = tq*4+w = h_{st-1};
        // after reduction lane b (b<8) holds batch b's dot (batch = lane&7)
        {
            int st = tq * 4 + w;
            if (st > 0) {
                float s = out_dot(sa0, sa1, wfc0, wfc1);
                if (lane < NB) ols[lane * OSTRIDE + (st - 1)] = s + bfc;
            }
        }
    }

    // final output column: h_511 lives in hbuf[0]
    if (w == 3) {
        const _Float16* hp = hbuf[0] + (c & 7) * HSTR + 8 * q;
        half8v a0 = *(const half8v*)(hp);
        half8v a1 = *(const half8v*)(hp + 32);
        float s = out_dot(a0, a1, wfc0, wfc1);
        if (lane < NB) ols[lane * OSTRIDE + (T_STEPS - 1)] = s + bfc;
    }
    __syncthreads();

    // bulk store: LDS out -> global, coalesced
    for (int i = tid; i < NB * T_STEPS; i += 256) {
        int b = i >> 9;
        int t = i & (T_STEPS - 1);
        out[(size_t)(b0 + b) * T_STEPS + t] = ols[b * OSTRIDE + t];
    }
}

extern "C" void kernel_launch(void* const* d_in, const int* in_sizes, int n_in,
                              void* d_out, int out_size, void* d_ws, size_t ws_size,
                              hipStream_t stream) {
    const float* x    = (const float*)d_in[0];
    const float* w_ih = (const float*)d_in[1];
    const float* w_hh = (const float*)d_in[2];
    const float* b_ih = (const float*)d_in[3];
    const float* b_hh = (const float*)d_in[4];
    const float* w_fc = (const float*)d_in[5];
    const float* b_fc = (const float*)d_in[6];
    float* out = (float*)d_out;
    hipLaunchKernelGGL(lstm_kernel, dim3(2048 / NB), dim3(256), 0, stream,
                       x, w_ih, w_hh, b_ih, b_hh, w_fc, b_fc, out);
}